// Round 1
// baseline (308.877 us; speedup 1.0000x reference)
//
#include <hip/hip_runtime.h>
#include <cmath>

#define NB 8
#define CC 256
#define NPIX 4096
#define QB 64
#define KVB 64

typedef __attribute__((ext_vector_type(4))) float f32x4;
typedef __attribute__((ext_vector_type(8))) short s16x8;
typedef __attribute__((ext_vector_type(4))) unsigned short u16x4;

__device__ __forceinline__ unsigned short f2bf(float f) {
    union { float f; unsigned int u; } v; v.f = f;
    return (unsigned short)((v.u + 0x7FFFu + ((v.u >> 16) & 1u)) >> 16);
}

// ---------------------------------------------------------------------------
// proj_qk: Q[b][n][32] = w1·x + b1 ;  K[b][m][32] = w2·x + b2   (bf16 out)
// grid: 8 batches x 16 n-chunks of 256, 256 threads
// ---------------------------------------------------------------------------
__global__ __launch_bounds__(256) void proj_qk_kernel(
    const float* __restrict__ x, const float* __restrict__ w1, const float* __restrict__ b1,
    const float* __restrict__ w2, const float* __restrict__ b2,
    unsigned short* __restrict__ Qm, unsigned short* __restrict__ Km)
{
    __shared__ float w1s[256 * 32];
    __shared__ float w2s[256 * 32];
    const int t = threadIdx.x;
    const int b = blockIdx.x >> 4;
    const int n0 = (blockIdx.x & 15) * 256;

#pragma unroll
    for (int i = 0; i < 32; ++i) {
        w1s[t * 32 + i] = w1[i * 256 + t];
        w2s[t * 32 + i] = w2[i * 256 + t];
    }
    __syncthreads();

    const int n = n0 + t;
    float qa[32], ka[32];
#pragma unroll
    for (int o = 0; o < 32; ++o) { qa[o] = 0.f; ka[o] = 0.f; }

    const float* xp = x + (size_t)b * CC * NPIX + n;
#pragma unroll 4
    for (int c = 0; c < 256; ++c) {
        float xv = xp[(size_t)c * NPIX];
        const f32x4* w1p = (const f32x4*)(&w1s[c * 32]);
        const f32x4* w2p = (const f32x4*)(&w2s[c * 32]);
#pragma unroll
        for (int o4 = 0; o4 < 8; ++o4) {
            f32x4 wq = w1p[o4], wk = w2p[o4];
            qa[o4 * 4 + 0] += wq[0] * xv; qa[o4 * 4 + 1] += wq[1] * xv;
            qa[o4 * 4 + 2] += wq[2] * xv; qa[o4 * 4 + 3] += wq[3] * xv;
            ka[o4 * 4 + 0] += wk[0] * xv; ka[o4 * 4 + 1] += wk[1] * xv;
            ka[o4 * 4 + 2] += wk[2] * xv; ka[o4 * 4 + 3] += wk[3] * xv;
        }
    }

    u16x4* qdst = (u16x4*)(Qm + (((size_t)b * NPIX) + n) * 32);
    u16x4* kdst = (u16x4*)(Km + (((size_t)b * NPIX) + n) * 32);
#pragma unroll
    for (int o4 = 0; o4 < 8; ++o4) {
        u16x4 pq, pk;
#pragma unroll
        for (int j = 0; j < 4; ++j) {
            pq[j] = f2bf(qa[o4 * 4 + j] + b1[o4 * 4 + j]);
            pk[j] = f2bf(ka[o4 * 4 + j] + b2[o4 * 4 + j]);
        }
        qdst[o4] = pq;
        kdst[o4] = pk;
    }
}

// ---------------------------------------------------------------------------
// proj_v: V[b][c][m] = w3·x + b3   (bf16 out, [c][m] layout = reference v)
// grid: 8 x 16 n-chunks x 4 co-chunks = 512 blocks, 256 threads
// ---------------------------------------------------------------------------
__global__ __launch_bounds__(256) void proj_v_kernel(
    const float* __restrict__ x, const float* __restrict__ w3, const float* __restrict__ b3,
    unsigned short* __restrict__ Vm)
{
    __shared__ float w3s[256 * 64];
    const int t = threadIdx.x;
    const int b = blockIdx.x >> 6;
    const int rem = blockIdx.x & 63;
    const int n0 = (rem & 15) * 256;
    const int co0 = (rem >> 4) * 64;

#pragma unroll
    for (int i = 0; i < 64; ++i)
        w3s[t * 64 + i] = w3[(size_t)(co0 + i) * 256 + t];
    __syncthreads();

    const int n = n0 + t;
    float acc[64];
#pragma unroll
    for (int o = 0; o < 64; ++o) acc[o] = 0.f;

    const float* xp = x + (size_t)b * CC * NPIX + n;
#pragma unroll 2
    for (int c = 0; c < 256; ++c) {
        float xv = xp[(size_t)c * NPIX];
        const f32x4* wp = (const f32x4*)(&w3s[c * 64]);
#pragma unroll
        for (int o4 = 0; o4 < 16; ++o4) {
            f32x4 wv = wp[o4];
            acc[o4 * 4 + 0] += wv[0] * xv; acc[o4 * 4 + 1] += wv[1] * xv;
            acc[o4 * 4 + 2] += wv[2] * xv; acc[o4 * 4 + 3] += wv[3] * xv;
        }
    }

#pragma unroll
    for (int o = 0; o < 64; ++o) {
        float v = acc[o] + b3[co0 + o];
        Vm[((size_t)b * CC + co0 + o) * NPIX + n] = f2bf(v);
    }
}

// ---------------------------------------------------------------------------
// attn: flash attention, S^T = mfma(K,Q) so softmax is lane-local; O^T = V·P^T
// grid: 512 blocks (8 batches x 64 q-blocks of 64), 256 threads = 4 waves
// wave grid 2(q) x 2(c): each wave 32 q-rows x 128 channels
// ---------------------------------------------------------------------------
__global__ __launch_bounds__(256, 2) void attn_kernel(
    const unsigned short* __restrict__ Qm, const unsigned short* __restrict__ Km,
    const unsigned short* __restrict__ Vm, const float* __restrict__ gamma,
    float* __restrict__ out)
{
    __shared__ unsigned short Ks[KVB * 32];     // [m][d]  4KB, linear
    __shared__ unsigned short Vs[CC * KVB];     // [c][m] 32KB, 16B-slot XOR swizzle
    __shared__ unsigned short Ps[4][32 * KVB];  // per-wave [q][m] 16KB, swizzled

    // XCD swizzle: each XCD gets one batch's 64 q-blocks (K+V fit its L2)
    const int bid = ((blockIdx.x & 7) << 6) + (blockIdx.x >> 3);
    const int b = bid >> 6;
    const int q0 = (bid & 63) * QB;

    const int t = threadIdx.x;
    const int wave = t >> 6;
    const int lane = t & 63;
    const int cl = lane & 15;
    const int g = lane >> 4;
    const int jq = wave >> 1;
    const int jc = wave & 1;
    const int qbase = q0 + jq * 32;
    const int c0 = jc * 128;

    // Q B-frags (persistent in regs): B[k=d][col=q] = Q[qrow][d]
    s16x8 qf[2];
#pragma unroll
    for (int qt = 0; qt < 2; ++qt)
        qf[qt] = *(const s16x8*)(Qm + (((size_t)b * NPIX) + qbase + qt * 16 + cl) * 32 + g * 8);

    f32x4 acc[2][8];
#pragma unroll
    for (int qt = 0; qt < 2; ++qt)
#pragma unroll
        for (int ct = 0; ct < 8; ++ct)
            acc[qt][ct] = (f32x4){0.f, 0.f, 0.f, 0.f};

    float mrun[2] = {-__builtin_inff(), -__builtin_inff()};
    float lrun[2] = {0.f, 0.f};

    const unsigned short* Kg = Km + (size_t)b * NPIX * 32;
    const unsigned short* Vg = Vm + (size_t)b * CC * NPIX;
    unsigned short* Pw = &Ps[wave][0];

    for (int m0 = 0; m0 < NPIX; m0 += KVB) {
        __syncthreads();  // previous iter's reads done before overwrite
        {   // stage K tile [64][32] linear
            const int kr = t >> 2, ks = (t & 3) * 8;
            *(s16x8*)(&Ks[kr * 32 + ks]) =
                *(const s16x8*)(Kg + (size_t)(m0 + kr) * 32 + ks);
        }
        {   // stage V tile [256][64], swizzled 16B slots
            const int vin = t & 7, vr0 = t >> 3;
#pragma unroll
            for (int i = 0; i < 8; ++i) {
                const int cr = vr0 + i * 32;
                *(s16x8*)(&Vs[cr * 64 + ((vin ^ (cr & 7)) << 3)]) =
                    *(const s16x8*)(Vg + (size_t)cr * NPIX + m0 + vin * 8);
            }
        }
        __syncthreads();

        // K A-frags (shared across qt): A[row=m][k=d]
        s16x8 kf[4];
#pragma unroll
        for (int mt = 0; mt < 4; ++mt)
            kf[mt] = *(const s16x8*)(&Ks[(mt * 16 + cl) * 32 + g * 8]);

#pragma unroll
        for (int qt = 0; qt < 2; ++qt) {
            // S^T tiles: D[row=m][col=q]
            f32x4 s[4];
#pragma unroll
            for (int mt = 0; mt < 4; ++mt) {
                f32x4 z = (f32x4){0.f, 0.f, 0.f, 0.f};
                s[mt] = __builtin_amdgcn_mfma_f32_16x16x32_bf16(kf[mt], qf[qt], z, 0, 0, 0);
            }
            // online softmax over m (rows + lane-groups): stats live at q = lane&15
            float ml = -__builtin_inff();
#pragma unroll
            for (int mt = 0; mt < 4; ++mt)
#pragma unroll
                for (int r = 0; r < 4; ++r) ml = fmaxf(ml, s[mt][r]);
            ml = fmaxf(ml, __shfl_xor(ml, 16, 64));
            ml = fmaxf(ml, __shfl_xor(ml, 32, 64));
            const float mnew = fmaxf(mrun[qt], ml);
            const float alpha = __expf(mrun[qt] - mnew);
            mrun[qt] = mnew;
            float sl = 0.f;
#pragma unroll
            for (int mt = 0; mt < 4; ++mt) {
#pragma unroll
                for (int r = 0; r < 4; ++r) {
                    s[mt][r] = __expf(s[mt][r] - mnew);
                    sl += s[mt][r];
                }
            }
            sl += __shfl_xor(sl, 16, 64);
            sl += __shfl_xor(sl, 32, 64);
            lrun[qt] = lrun[qt] * alpha + sl;
#pragma unroll
            for (int ct = 0; ct < 8; ++ct) acc[qt][ct] *= alpha;

            // pack P -> wave-private LDS, [q][m] swizzled (8B writes, XOR mult of 8)
            const int qrow = qt * 16 + cl;
#pragma unroll
            for (int mt = 0; mt < 4; ++mt) {
                u16x4 pk;
#pragma unroll
                for (int r = 0; r < 4; ++r) pk[r] = f2bf(s[mt][r]);
                *(u16x4*)(&Pw[qrow * 64 + ((mt * 16 + g * 4) ^ ((qrow & 7) << 3))]) = pk;
            }
        }

        // PV: acc[qt][ct] += mfma(A=V[c][m], B=P^T[m][q])
#pragma unroll
        for (int ch = 0; ch < 2; ++ch) {
            s16x8 pb[2];
#pragma unroll
            for (int qt = 0; qt < 2; ++qt) {
                const int qrow = qt * 16 + cl;
                pb[qt] = *(const s16x8*)(&Pw[qrow * 64 + ((ch * 32 + g * 8) ^ ((qrow & 7) << 3))]);
            }
#pragma unroll
            for (int ct = 0; ct < 8; ++ct) {
                const int cr = c0 + ct * 16 + cl;
                s16x8 av = *(const s16x8*)(&Vs[cr * 64 + ((ch * 32 + g * 8) ^ ((cr & 7) << 3))]);
#pragma unroll
                for (int qt = 0; qt < 2; ++qt)
                    acc[qt][ct] = __builtin_amdgcn_mfma_f32_16x16x32_bf16(av, pb[qt], acc[qt][ct], 0, 0, 0);
            }
        }
    }

    // epilogue: O^T layout -> coalesced [b][c][n] stores; second output = gamma*val
    const float gm = gamma[0];
    float* out2 = out + (size_t)NB * CC * NPIX;
#pragma unroll
    for (int qt = 0; qt < 2; ++qt) {
        const float inv = 1.f / lrun[qt];
        const int n = qbase + qt * 16 + cl;
#pragma unroll
        for (int ct = 0; ct < 8; ++ct) {
#pragma unroll
            for (int r = 0; r < 4; ++r) {
                const int chn = c0 + ct * 16 + g * 4 + r;
                const float val = acc[qt][ct][r] * inv;
                const size_t idx = ((size_t)b * CC + chn) * NPIX + n;
                out[idx] = val;
                out2[idx] = gm * val;
            }
        }
    }
}

// ---------------------------------------------------------------------------
extern "C" void kernel_launch(void* const* d_in, const int* in_sizes, int n_in,
                              void* d_out, int out_size, void* d_ws, size_t ws_size,
                              hipStream_t stream) {
    (void)in_sizes; (void)n_in; (void)out_size; (void)ws_size;
    const float* x     = (const float*)d_in[0];
    const float* w1    = (const float*)d_in[1];
    const float* b1    = (const float*)d_in[2];
    const float* w2    = (const float*)d_in[3];
    const float* b2    = (const float*)d_in[4];
    const float* w3    = (const float*)d_in[5];
    const float* b3    = (const float*)d_in[6];
    const float* gamma = (const float*)d_in[7];
    float* out = (float*)d_out;

    unsigned short* Qm = (unsigned short*)d_ws;                       // 2 MB
    unsigned short* Km = Qm + (size_t)NB * NPIX * 32;                 // 2 MB
    unsigned short* Vm = Km + (size_t)NB * NPIX * 32;                 // 16 MB

    proj_qk_kernel<<<NB * 16, 256, 0, stream>>>(x, w1, b1, w2, b2, Qm, Km);
    proj_v_kernel<<<NB * 64, 256, 0, stream>>>(x, w3, b3, Vm);
    attn_kernel<<<NB * 64, 256, 0, stream>>>(Qm, Km, Vm, gamma, out);
}

// Round 2
// 308.616 us; speedup vs baseline: 1.0008x; 1.0008x over previous
//
#include <hip/hip_runtime.h>
#include <cmath>

#define NB 8
#define CC 256
#define NPIX 4096
#define QB 64
#define KVB 64

typedef __attribute__((ext_vector_type(4))) float f32x4;
typedef __attribute__((ext_vector_type(8))) short s16x8;
typedef __attribute__((ext_vector_type(4))) unsigned short u16x4;

__device__ __forceinline__ unsigned short f2bf(float f) {
    union { float f; unsigned int u; } v; v.f = f;
    return (unsigned short)((v.u + 0x7FFFu + ((v.u >> 16) & 1u)) >> 16);
}

// ---------------------------------------------------------------------------
// proj_qk: Q[b][n][32] = w1·x + b1 ;  K[b][m][32] = w2·x + b2   (bf16 out)
// grid: 8 batches x 16 n-chunks of 256, 256 threads
// ---------------------------------------------------------------------------
__global__ __launch_bounds__(256) void proj_qk_kernel(
    const float* __restrict__ x, const float* __restrict__ w1, const float* __restrict__ b1,
    const float* __restrict__ w2, const float* __restrict__ b2,
    unsigned short* __restrict__ Qm, unsigned short* __restrict__ Km)
{
    __shared__ float w1s[256 * 32];
    __shared__ float w2s[256 * 32];
    const int t = threadIdx.x;
    const int b = blockIdx.x >> 4;
    const int n0 = (blockIdx.x & 15) * 256;

#pragma unroll
    for (int i = 0; i < 32; ++i) {
        w1s[t * 32 + i] = w1[i * 256 + t];
        w2s[t * 32 + i] = w2[i * 256 + t];
    }
    __syncthreads();

    const int n = n0 + t;
    float qa[32], ka[32];
#pragma unroll
    for (int o = 0; o < 32; ++o) { qa[o] = 0.f; ka[o] = 0.f; }

    const float* xp = x + (size_t)b * CC * NPIX + n;
#pragma unroll 4
    for (int c = 0; c < 256; ++c) {
        float xv = xp[(size_t)c * NPIX];
        const f32x4* w1p = (const f32x4*)(&w1s[c * 32]);
        const f32x4* w2p = (const f32x4*)(&w2s[c * 32]);
#pragma unroll
        for (int o4 = 0; o4 < 8; ++o4) {
            f32x4 wq = w1p[o4], wk = w2p[o4];
            qa[o4 * 4 + 0] += wq[0] * xv; qa[o4 * 4 + 1] += wq[1] * xv;
            qa[o4 * 4 + 2] += wq[2] * xv; qa[o4 * 4 + 3] += wq[3] * xv;
            ka[o4 * 4 + 0] += wk[0] * xv; ka[o4 * 4 + 1] += wk[1] * xv;
            ka[o4 * 4 + 2] += wk[2] * xv; ka[o4 * 4 + 3] += wk[3] * xv;
        }
    }

    u16x4* qdst = (u16x4*)(Qm + (((size_t)b * NPIX) + n) * 32);
    u16x4* kdst = (u16x4*)(Km + (((size_t)b * NPIX) + n) * 32);
#pragma unroll
    for (int o4 = 0; o4 < 8; ++o4) {
        u16x4 pq, pk;
#pragma unroll
        for (int j = 0; j < 4; ++j) {
            pq[j] = f2bf(qa[o4 * 4 + j] + b1[o4 * 4 + j]);
            pk[j] = f2bf(ka[o4 * 4 + j] + b2[o4 * 4 + j]);
        }
        qdst[o4] = pq;
        kdst[o4] = pk;
    }
}

// ---------------------------------------------------------------------------
// proj_v: V[b][c][m] = w3·x + b3   (bf16 out, [c][m] layout = reference v)
// grid: 8 x 16 n-chunks x 4 co-chunks = 512 blocks, 256 threads
// ---------------------------------------------------------------------------
__global__ __launch_bounds__(256) void proj_v_kernel(
    const float* __restrict__ x, const float* __restrict__ w3, const float* __restrict__ b3,
    unsigned short* __restrict__ Vm)
{
    __shared__ float w3s[256 * 64];
    const int t = threadIdx.x;
    const int b = blockIdx.x >> 6;
    const int rem = blockIdx.x & 63;
    const int n0 = (rem & 15) * 256;
    const int co0 = (rem >> 4) * 64;

#pragma unroll
    for (int i = 0; i < 64; ++i)
        w3s[t * 64 + i] = w3[(size_t)(co0 + i) * 256 + t];
    __syncthreads();

    const int n = n0 + t;
    float acc[64];
#pragma unroll
    for (int o = 0; o < 64; ++o) acc[o] = 0.f;

    const float* xp = x + (size_t)b * CC * NPIX + n;
#pragma unroll 2
    for (int c = 0; c < 256; ++c) {
        float xv = xp[(size_t)c * NPIX];
        const f32x4* wp = (const f32x4*)(&w3s[c * 64]);
#pragma unroll
        for (int o4 = 0; o4 < 16; ++o4) {
            f32x4 wv = wp[o4];
            acc[o4 * 4 + 0] += wv[0] * xv; acc[o4 * 4 + 1] += wv[1] * xv;
            acc[o4 * 4 + 2] += wv[2] * xv; acc[o4 * 4 + 3] += wv[3] * xv;
        }
    }

#pragma unroll
    for (int o = 0; o < 64; ++o) {
        float v = acc[o] + b3[co0 + o];
        Vm[((size_t)b * CC + co0 + o) * NPIX + n] = f2bf(v);
    }
}

// ---------------------------------------------------------------------------
// attn: flash attention, S^T = mfma(K,Q) so softmax is lane-local; O^T = V·P^T
// grid: 512 blocks (8 batches x 64 q-blocks of 64), 256 threads = 4 waves
// wave grid 2(q) x 2(c): each wave 32 q-rows x 128 channels
// ---------------------------------------------------------------------------
__global__ __launch_bounds__(256, 2) void attn_kernel(
    const unsigned short* __restrict__ Qm, const unsigned short* __restrict__ Km,
    const unsigned short* __restrict__ Vm, const float* __restrict__ gamma,
    float* __restrict__ out)
{
    __shared__ unsigned short Ks[KVB * 32];     // [m][d]  4KB, linear
    __shared__ unsigned short Vs[CC * KVB];     // [c][m] 32KB, 16B-slot XOR swizzle
    __shared__ unsigned short Ps[4][32 * KVB];  // per-wave [q][m] 16KB, swizzled

    // XCD swizzle: each XCD gets one batch's 64 q-blocks (K+V fit its L2)
    const int bid = ((blockIdx.x & 7) << 6) + (blockIdx.x >> 3);
    const int b = bid >> 6;
    const int q0 = (bid & 63) * QB;

    const int t = threadIdx.x;
    const int wave = t >> 6;
    const int lane = t & 63;
    const int cl = lane & 15;
    const int g = lane >> 4;
    const int jq = wave >> 1;
    const int jc = wave & 1;
    const int qbase = q0 + jq * 32;
    const int c0 = jc * 128;

    // Q B-frags (persistent in regs): B[k=d][col=q] = Q[qrow][d]
    s16x8 qf[2];
#pragma unroll
    for (int qt = 0; qt < 2; ++qt)
        qf[qt] = *(const s16x8*)(Qm + (((size_t)b * NPIX) + qbase + qt * 16 + cl) * 32 + g * 8);

    f32x4 acc[2][8];
#pragma unroll
    for (int qt = 0; qt < 2; ++qt)
#pragma unroll
        for (int ct = 0; ct < 8; ++ct)
            acc[qt][ct] = (f32x4){0.f, 0.f, 0.f, 0.f};

    float mrun[2] = {-__builtin_inff(), -__builtin_inff()};
    float lrun[2] = {0.f, 0.f};

    const unsigned short* Kg = Km + (size_t)b * NPIX * 32;
    const unsigned short* Vg = Vm + (size_t)b * CC * NPIX;
    unsigned short* Pw = &Ps[wave][0];

    for (int m0 = 0; m0 < NPIX; m0 += KVB) {
        __syncthreads();  // previous iter's reads done before overwrite
        {   // stage K tile [64][32] linear
            const int kr = t >> 2, ks = (t & 3) * 8;
            *(s16x8*)(&Ks[kr * 32 + ks]) =
                *(const s16x8*)(Kg + (size_t)(m0 + kr) * 32 + ks);
        }
        {   // stage V tile [256][64], swizzled 16B slots
            const int vin = t & 7, vr0 = t >> 3;
#pragma unroll
            for (int i = 0; i < 8; ++i) {
                const int cr = vr0 + i * 32;
                *(s16x8*)(&Vs[cr * 64 + ((vin ^ (cr & 7)) << 3)]) =
                    *(const s16x8*)(Vg + (size_t)cr * NPIX + m0 + vin * 8);
            }
        }
        __syncthreads();

        // K A-frags (shared across qt): A[row=m][k=d]
        s16x8 kf[4];
#pragma unroll
        for (int mt = 0; mt < 4; ++mt)
            kf[mt] = *(const s16x8*)(&Ks[(mt * 16 + cl) * 32 + g * 8]);

#pragma unroll
        for (int qt = 0; qt < 2; ++qt) {
            // S^T tiles: D[row=m][col=q]
            f32x4 s[4];
#pragma unroll
            for (int mt = 0; mt < 4; ++mt) {
                f32x4 z = (f32x4){0.f, 0.f, 0.f, 0.f};
                s[mt] = __builtin_amdgcn_mfma_f32_16x16x32_bf16(kf[mt], qf[qt], z, 0, 0, 0);
            }
            // online softmax over m (rows + lane-groups): stats live at q = lane&15
            float ml = -__builtin_inff();
#pragma unroll
            for (int mt = 0; mt < 4; ++mt)
#pragma unroll
                for (int r = 0; r < 4; ++r) ml = fmaxf(ml, s[mt][r]);
            ml = fmaxf(ml, __shfl_xor(ml, 16, 64));
            ml = fmaxf(ml, __shfl_xor(ml, 32, 64));
            const float mnew = fmaxf(mrun[qt], ml);
            const float alpha = __expf(mrun[qt] - mnew);
            mrun[qt] = mnew;
            float sl = 0.f;
#pragma unroll
            for (int mt = 0; mt < 4; ++mt) {
#pragma unroll
                for (int r = 0; r < 4; ++r) {
                    s[mt][r] = __expf(s[mt][r] - mnew);
                    sl += s[mt][r];
                }
            }
            sl += __shfl_xor(sl, 16, 64);
            sl += __shfl_xor(sl, 32, 64);
            lrun[qt] = lrun[qt] * alpha + sl;
#pragma unroll
            for (int ct = 0; ct < 8; ++ct) acc[qt][ct] *= alpha;

            // pack P -> wave-private LDS, [q][m] swizzled (8B writes, XOR mult of 8)
            const int qrow = qt * 16 + cl;
#pragma unroll
            for (int mt = 0; mt < 4; ++mt) {
                u16x4 pk;
#pragma unroll
                for (int r = 0; r < 4; ++r) pk[r] = f2bf(s[mt][r]);
                *(u16x4*)(&Pw[qrow * 64 + ((mt * 16 + g * 4) ^ ((qrow & 7) << 3))]) = pk;
            }
        }

        // PV: acc[qt][ct] += mfma(A=V[c][m], B=P^T[m][q])
#pragma unroll
        for (int ch = 0; ch < 2; ++ch) {
            s16x8 pb[2];
#pragma unroll
            for (int qt = 0; qt < 2; ++qt) {
                const int qrow = qt * 16 + cl;
                pb[qt] = *(const s16x8*)(&Pw[qrow * 64 + ((ch * 32 + g * 8) ^ ((qrow & 7) << 3))]);
            }
#pragma unroll
            for (int ct = 0; ct < 8; ++ct) {
                const int cr = c0 + ct * 16 + cl;
                s16x8 av = *(const s16x8*)(&Vs[cr * 64 + ((ch * 32 + g * 8) ^ ((cr & 7) << 3))]);
#pragma unroll
                for (int qt = 0; qt < 2; ++qt)
                    acc[qt][ct] = __builtin_amdgcn_mfma_f32_16x16x32_bf16(av, pb[qt], acc[qt][ct], 0, 0, 0);
            }
        }
    }

    // epilogue: O^T layout -> coalesced [b][c][n] stores; second output = gamma*val
    const float gm = gamma[0];
    float* out2 = out + (size_t)NB * CC * NPIX;
#pragma unroll
    for (int qt = 0; qt < 2; ++qt) {
        const float inv = 1.f / lrun[qt];
        const int n = qbase + qt * 16 + cl;
#pragma unroll
        for (int ct = 0; ct < 8; ++ct) {
#pragma unroll
            for (int r = 0; r < 4; ++r) {
                const int chn = c0 + ct * 16 + g * 4 + r;
                const float val = acc[qt][ct][r] * inv;
                const size_t idx = ((size_t)b * CC + chn) * NPIX + n;
                out[idx] = val;
                out2[idx] = gm * val;
            }
        }
    }
}

// ---------------------------------------------------------------------------
extern "C" void kernel_launch(void* const* d_in, const int* in_sizes, int n_in,
                              void* d_out, int out_size, void* d_ws, size_t ws_size,
                              hipStream_t stream) {
    (void)in_sizes; (void)n_in; (void)out_size; (void)ws_size;
    const float* x     = (const float*)d_in[0];
    const float* w1    = (const float*)d_in[1];
    const float* b1    = (const float*)d_in[2];
    const float* w2    = (const float*)d_in[3];
    const float* b2    = (const float*)d_in[4];
    const float* w3    = (const float*)d_in[5];
    const float* b3    = (const float*)d_in[6];
    const float* gamma = (const float*)d_in[7];
    float* out = (float*)d_out;

    unsigned short* Qm = (unsigned short*)d_ws;                       // 2 MB
    unsigned short* Km = Qm + (size_t)NB * NPIX * 32;                 // 2 MB
    unsigned short* Vm = Km + (size_t)NB * NPIX * 32;                 // 16 MB

    proj_qk_kernel<<<NB * 16, 256, 0, stream>>>(x, w1, b1, w2, b2, Qm, Km);
    proj_v_kernel<<<NB * 64, 256, 0, stream>>>(x, w3, b3, Vm);
    attn_kernel<<<NB * 64, 256, 0, stream>>>(Qm, Km, Vm, gamma, out);
}

// Round 3
// 172.233 us; speedup vs baseline: 1.7934x; 1.7918x over previous
//
#include <hip/hip_runtime.h>
#include <cmath>

#define NB 8
#define CC 256
#define NPIX 4096
#define QB 64
#define KVB 64
#define LOG2E 1.4426950408889634f

typedef __attribute__((ext_vector_type(4))) float f32x4;
typedef __attribute__((ext_vector_type(8))) short s16x8;
typedef __attribute__((ext_vector_type(4))) unsigned short u16x4;
typedef __attribute__((ext_vector_type(4))) unsigned int u32x4;
typedef __attribute__((ext_vector_type(2))) unsigned int u32x2;

__device__ __forceinline__ unsigned short f2bf(float f) {
    union { float f; unsigned int u; } v; v.f = f;
    return (unsigned short)((v.u + 0x7FFFu + ((v.u >> 16) & 1u)) >> 16);
}

__device__ __forceinline__ unsigned int cvt_pk_bf16(float lo, float hi) {
    unsigned int r;
    asm("v_cvt_pk_bf16_f32 %0, %1, %2" : "=v"(r) : "v"(lo), "v"(hi));
    return r;  // low16 = bf16(lo), high16 = bf16(hi), RNE
}

__device__ __forceinline__ float u2f(unsigned int u) {
    union { unsigned int u; float f; } v; v.u = u; return v.f;
}

// ---------------------------------------------------------------------------
// proj_gemm: [Q(32);K(32);V(256)] = W · x  via MFMA, 2-term x hi/lo split.
// M=320 (5 waves x 64co), N=64 per block, K=256. No LDS: A-frags direct from
// W (row-major, 16B contig), B-frags as 8 coalesced scalar f32 loads along c.
// Q rows pre-scaled by log2e so attention can use exp2 directly.
// grid: 8 batches x 64 n-tiles = 512 blocks, 320 threads.
// ---------------------------------------------------------------------------
__global__ __launch_bounds__(320) void proj_gemm_kernel(
    const float* __restrict__ x,
    const float* __restrict__ w1, const float* __restrict__ b1,
    const float* __restrict__ w2, const float* __restrict__ b2,
    const float* __restrict__ w3, const float* __restrict__ b3,
    unsigned short* __restrict__ Qm, unsigned short* __restrict__ Km,
    unsigned short* __restrict__ Vm)
{
    const int b  = blockIdx.x >> 6;
    const int n0 = (blockIdx.x & 63) * 64;
    const int wave = threadIdx.x >> 6;
    const int lane = threadIdx.x & 63;
    const int cl = lane & 15, g = lane >> 4;

    // per-(ct) weight row pointer for this lane (tiles never straddle w1/w2/w3)
    const float* arow[4];
#pragma unroll
    for (int ct = 0; ct < 4; ++ct) {
        const int row = wave * 64 + ct * 16 + cl;  // 0..319
        if (row < 32)       arow[ct] = w1 + (size_t)row * 256;
        else if (row < 64)  arow[ct] = w2 + (size_t)(row - 32) * 256;
        else                arow[ct] = w3 + (size_t)(row - 64) * 256;
    }

    const float* xb = x + (size_t)b * CC * NPIX + n0 + cl;

    f32x4 acc[4][4];
#pragma unroll
    for (int ct = 0; ct < 4; ++ct)
#pragma unroll
        for (int nt = 0; nt < 4; ++nt) acc[ct][nt] = (f32x4){0.f, 0.f, 0.f, 0.f};

    for (int ks = 0; ks < 8; ++ks) {
        const int c0 = ks * 32;
        // A-frags (hi only): W[row][c0+g*8 .. +8], contiguous
        s16x8 ah[4];
#pragma unroll
        for (int ct = 0; ct < 4; ++ct) {
            const float* ap = arow[ct] + c0 + g * 8;
            f32x4 a0 = *(const f32x4*)ap;
            f32x4 a1 = *(const f32x4*)(ap + 4);
            u32x4 u;
            u[0] = cvt_pk_bf16(a0[0], a0[1]); u[1] = cvt_pk_bf16(a0[2], a0[3]);
            u[2] = cvt_pk_bf16(a1[0], a1[1]); u[3] = cvt_pk_bf16(a1[2], a1[3]);
            ah[ct] = __builtin_bit_cast(s16x8, u);
        }
#pragma unroll
        for (int nt = 0; nt < 4; ++nt) {
            // B-frag: x[c0+g*8+e][n0+nt*16+cl], e=0..7 (coalesced across cl)
            const float* xp = xb + (size_t)(c0 + g * 8) * NPIX + nt * 16;
            float xe[8];
#pragma unroll
            for (int e = 0; e < 8; ++e) xe[e] = xp[(size_t)e * NPIX];
            u32x4 uh, ul;
#pragma unroll
            for (int p = 0; p < 4; ++p) {
                const unsigned int hp = cvt_pk_bf16(xe[2 * p], xe[2 * p + 1]);
                const float h0 = u2f(hp << 16);
                const float h1 = u2f(hp & 0xffff0000u);
                uh[p] = hp;
                ul[p] = cvt_pk_bf16(xe[2 * p] - h0, xe[2 * p + 1] - h1);
            }
            const s16x8 bh = __builtin_bit_cast(s16x8, uh);
            const s16x8 bl = __builtin_bit_cast(s16x8, ul);
#pragma unroll
            for (int ct = 0; ct < 4; ++ct)
                acc[ct][nt] = __builtin_amdgcn_mfma_f32_16x16x32_bf16(ah[ct], bh, acc[ct][nt], 0, 0, 0);
#pragma unroll
            for (int ct = 0; ct < 4; ++ct)
                acc[ct][nt] = __builtin_amdgcn_mfma_f32_16x16x32_bf16(ah[ct], bl, acc[ct][nt], 0, 0, 0);
        }
    }

    // epilogue: D layout col=lane&15(=n), row=(lane>>4)*4+r(=co)
    if (wave == 0) {
#pragma unroll
        for (int ct = 0; ct < 4; ++ct) {
#pragma unroll
            for (int nt = 0; nt < 4; ++nt) {
                const int n = n0 + nt * 16 + cl;
                const int co = ct * 16 + g * 4;
                f32x4 v = acc[ct][nt];
                if (ct < 2) {  // Q rows 0..31, pre-scale by log2e for exp2 softmax
                    const float q0 = (v[0] + b1[co + 0]) * LOG2E;
                    const float q1 = (v[1] + b1[co + 1]) * LOG2E;
                    const float q2 = (v[2] + b1[co + 2]) * LOG2E;
                    const float q3 = (v[3] + b1[co + 3]) * LOG2E;
                    u32x2 dd = {cvt_pk_bf16(q0, q1), cvt_pk_bf16(q2, q3)};
                    *(u32x2*)(Qm + ((size_t)b * NPIX + n) * 32 + co) = dd;
                } else {       // K rows 32..63
                    const int ko = co - 32;
                    const float k0 = v[0] + b2[ko + 0];
                    const float k1 = v[1] + b2[ko + 1];
                    const float k2 = v[2] + b2[ko + 2];
                    const float k3 = v[3] + b2[ko + 3];
                    u32x2 dd = {cvt_pk_bf16(k0, k1), cvt_pk_bf16(k2, k3)};
                    *(u32x2*)(Km + ((size_t)b * NPIX + n) * 32 + ko) = dd;
                }
            }
        }
    } else {
        const int cvb = (wave - 1) * 64;
#pragma unroll
        for (int ct = 0; ct < 4; ++ct) {
#pragma unroll
            for (int nt = 0; nt < 4; ++nt) {
                const int n = n0 + nt * 16 + cl;
                const int cv = cvb + ct * 16 + g * 4;
#pragma unroll
                for (int r = 0; r < 4; ++r)
                    Vm[((size_t)b * CC + cv + r) * NPIX + n] = f2bf(acc[ct][nt][r] + b3[cv + r]);
            }
        }
    }
}

// ---------------------------------------------------------------------------
// attn: flash attention, S^T = mfma(K,Q) so softmax is lane-local; O^T = V·P^T
// Q pre-scaled by log2e -> exp2 softmax. Defer-max (THR=8, log2 domain).
// grid: 512 blocks (8 batches x 64 q-blocks of 64), 256 threads = 4 waves
// ---------------------------------------------------------------------------
__global__ __launch_bounds__(256, 2) void attn_kernel(
    const unsigned short* __restrict__ Qm, const unsigned short* __restrict__ Km,
    const unsigned short* __restrict__ Vm, const float* __restrict__ gamma,
    float* __restrict__ out)
{
    __shared__ unsigned short Ks[KVB * 32];     // [m][d]  4KB, linear
    __shared__ unsigned short Vs[CC * KVB];     // [c][m] 32KB, 16B-slot XOR swizzle
    __shared__ unsigned short Ps[4][32 * KVB];  // per-wave [q][m] 16KB, swizzled

    // XCD swizzle: each XCD gets one batch's 64 q-blocks (K+V fit its L2)
    const int bid = ((blockIdx.x & 7) << 6) + (blockIdx.x >> 3);
    const int b = bid >> 6;
    const int q0 = (bid & 63) * QB;

    const int t = threadIdx.x;
    const int wave = t >> 6;
    const int lane = t & 63;
    const int cl = lane & 15;
    const int g = lane >> 4;
    const int jq = wave >> 1;
    const int jc = wave & 1;
    const int qbase = q0 + jq * 32;
    const int c0 = jc * 128;

    // Q B-frags (persistent in regs): B[k=d][col=q] = Q[qrow][d]
    s16x8 qf[2];
#pragma unroll
    for (int qt = 0; qt < 2; ++qt)
        qf[qt] = *(const s16x8*)(Qm + (((size_t)b * NPIX) + qbase + qt * 16 + cl) * 32 + g * 8);

    f32x4 acc[2][8];
#pragma unroll
    for (int qt = 0; qt < 2; ++qt)
#pragma unroll
        for (int ct = 0; ct < 8; ++ct)
            acc[qt][ct] = (f32x4){0.f, 0.f, 0.f, 0.f};

    float mrun[2] = {-__builtin_inff(), -__builtin_inff()};
    float lrun[2] = {0.f, 0.f};

    const unsigned short* Kg = Km + (size_t)b * NPIX * 32;
    const unsigned short* Vg = Vm + (size_t)b * CC * NPIX;
    unsigned short* Pw = &Ps[wave][0];

    for (int m0 = 0; m0 < NPIX; m0 += KVB) {
        __syncthreads();  // previous iter's reads done before overwrite
        {   // stage K tile [64][32] linear
            const int kr = t >> 2, ks = (t & 3) * 8;
            *(s16x8*)(&Ks[kr * 32 + ks]) =
                *(const s16x8*)(Kg + (size_t)(m0 + kr) * 32 + ks);
        }
        {   // stage V tile [256][64], swizzled 16B slots
            const int vin = t & 7, vr0 = t >> 3;
#pragma unroll
            for (int i = 0; i < 8; ++i) {
                const int cr = vr0 + i * 32;
                *(s16x8*)(&Vs[cr * 64 + ((vin ^ (cr & 7)) << 3)]) =
                    *(const s16x8*)(Vg + (size_t)cr * NPIX + m0 + vin * 8);
            }
        }
        __syncthreads();

        // K A-frags (shared across qt): A[row=m][k=d]
        s16x8 kf[4];
#pragma unroll
        for (int mt = 0; mt < 4; ++mt)
            kf[mt] = *(const s16x8*)(&Ks[(mt * 16 + cl) * 32 + g * 8]);

#pragma unroll
        for (int qt = 0; qt < 2; ++qt) {
            // S^T tiles: D[row=m][col=q]
            f32x4 s[4];
            __builtin_amdgcn_s_setprio(1);
#pragma unroll
            for (int mt = 0; mt < 4; ++mt) {
                f32x4 z = (f32x4){0.f, 0.f, 0.f, 0.f};
                s[mt] = __builtin_amdgcn_mfma_f32_16x16x32_bf16(kf[mt], qf[qt], z, 0, 0, 0);
            }
            __builtin_amdgcn_s_setprio(0);
            // online softmax over m (rows + lane-groups): stats live at q = lane&15
            float ml = -__builtin_inff();
#pragma unroll
            for (int mt = 0; mt < 4; ++mt)
#pragma unroll
                for (int r = 0; r < 4; ++r) ml = fmaxf(ml, s[mt][r]);
            ml = fmaxf(ml, __shfl_xor(ml, 16, 64));
            ml = fmaxf(ml, __shfl_xor(ml, 32, 64));
            // defer-max (T13): only rescale when max grew past THR (log2 domain)
            if (!__all(ml <= mrun[qt] + 8.f)) {
                const float mnew = fmaxf(mrun[qt], ml);
                const float alpha = __builtin_amdgcn_exp2f(mrun[qt] - mnew);
                mrun[qt] = mnew;
                lrun[qt] *= alpha;
#pragma unroll
                for (int ct = 0; ct < 8; ++ct) acc[qt][ct] *= alpha;
            }
            float sl = 0.f;
#pragma unroll
            for (int mt = 0; mt < 4; ++mt) {
#pragma unroll
                for (int r = 0; r < 4; ++r) {
                    s[mt][r] = __builtin_amdgcn_exp2f(s[mt][r] - mrun[qt]);
                    sl += s[mt][r];
                }
            }
            sl += __shfl_xor(sl, 16, 64);
            sl += __shfl_xor(sl, 32, 64);
            lrun[qt] += sl;

            // pack P -> wave-private LDS, [q][m] swizzled (8B writes via cvt_pk)
            const int qrow = qt * 16 + cl;
#pragma unroll
            for (int mt = 0; mt < 4; ++mt) {
                u32x2 dd = {cvt_pk_bf16(s[mt][0], s[mt][1]),
                            cvt_pk_bf16(s[mt][2], s[mt][3])};
                *(u32x2*)(&Pw[qrow * 64 + ((mt * 16 + g * 4) ^ ((qrow & 7) << 3))]) = dd;
            }
        }

        // PV: acc[qt][ct] += mfma(A=V[c][m], B=P^T[m][q])
#pragma unroll
        for (int ch = 0; ch < 2; ++ch) {
            s16x8 pb[2];
#pragma unroll
            for (int qt = 0; qt < 2; ++qt) {
                const int qrow = qt * 16 + cl;
                pb[qt] = *(const s16x8*)(&Pw[qrow * 64 + ((ch * 32 + g * 8) ^ ((qrow & 7) << 3))]);
            }
            __builtin_amdgcn_s_setprio(1);
#pragma unroll
            for (int ct = 0; ct < 8; ++ct) {
                const int cr = c0 + ct * 16 + cl;
                s16x8 av = *(const s16x8*)(&Vs[cr * 64 + ((ch * 32 + g * 8) ^ ((cr & 7) << 3))]);
#pragma unroll
                for (int qt = 0; qt < 2; ++qt)
                    acc[qt][ct] = __builtin_amdgcn_mfma_f32_16x16x32_bf16(av, pb[qt], acc[qt][ct], 0, 0, 0);
            }
            __builtin_amdgcn_s_setprio(0);
        }
    }

    // epilogue: O^T layout -> coalesced [b][c][n] stores; second output = gamma*val
    const float gm = gamma[0];
    float* out2 = out + (size_t)NB * CC * NPIX;
#pragma unroll
    for (int qt = 0; qt < 2; ++qt) {
        const float inv = 1.f / lrun[qt];
        const int n = qbase + qt * 16 + cl;
#pragma unroll
        for (int ct = 0; ct < 8; ++ct) {
#pragma unroll
            for (int r = 0; r < 4; ++r) {
                const int chn = c0 + ct * 16 + g * 4 + r;
                const float val = acc[qt][ct][r] * inv;
                const size_t idx = ((size_t)b * CC + chn) * NPIX + n;
                out[idx] = val;
                out2[idx] = gm * val;
            }
        }
    }
}

// ---------------------------------------------------------------------------
extern "C" void kernel_launch(void* const* d_in, const int* in_sizes, int n_in,
                              void* d_out, int out_size, void* d_ws, size_t ws_size,
                              hipStream_t stream) {
    (void)in_sizes; (void)n_in; (void)out_size; (void)ws_size;
    const float* x     = (const float*)d_in[0];
    const float* w1    = (const float*)d_in[1];
    const float* b1    = (const float*)d_in[2];
    const float* w2    = (const float*)d_in[3];
    const float* b2    = (const float*)d_in[4];
    const float* w3    = (const float*)d_in[5];
    const float* b3    = (const float*)d_in[6];
    const float* gamma = (const float*)d_in[7];
    float* out = (float*)d_out;

    unsigned short* Qm = (unsigned short*)d_ws;                       // 2 MB
    unsigned short* Km = Qm + (size_t)NB * NPIX * 32;                 // 2 MB
    unsigned short* Vm = Km + (size_t)NB * NPIX * 32;                 // 16 MB

    proj_gemm_kernel<<<NB * 64, 320, 0, stream>>>(x, w1, b1, w2, b2, w3, b3, Qm, Km, Vm);
    attn_kernel<<<NB * 64, 256, 0, stream>>>(Qm, Km, Vm, gamma, out);
}

// Round 4
// 159.984 us; speedup vs baseline: 1.9307x; 1.0766x over previous
//
#include <hip/hip_runtime.h>
#include <cmath>

#define NB 8
#define CC 256
#define NPIX 4096
#define QB 64
#define KVB 64
#define LOG2E 1.4426950408889634f

typedef __attribute__((ext_vector_type(4))) float f32x4;
typedef __attribute__((ext_vector_type(8))) short s16x8;
typedef __attribute__((ext_vector_type(4))) unsigned short u16x4;
typedef __attribute__((ext_vector_type(4))) unsigned int u32x4;
typedef __attribute__((ext_vector_type(2))) unsigned int u32x2;

__device__ __forceinline__ unsigned short f2bf(float f) {
    union { float f; unsigned int u; } v; v.f = f;
    return (unsigned short)((v.u + 0x7FFFu + ((v.u >> 16) & 1u)) >> 16);
}

__device__ __forceinline__ unsigned int cvt_pk_bf16(float lo, float hi) {
    unsigned int r;
    asm("v_cvt_pk_bf16_f32 %0, %1, %2" : "=v"(r) : "v"(lo), "v"(hi));
    return r;  // low16 = bf16(lo), high16 = bf16(hi), RNE
}

__device__ __forceinline__ float u2f(unsigned int u) {
    union { unsigned int u; float f; } v; v.u = u; return v.f;
}

// ---------------------------------------------------------------------------
// proj_gemm: [Q(32);K(32);V(256)] = W · x  via MFMA, 2-term x hi/lo split.
// (unchanged from R3 — ~14 µs)
// ---------------------------------------------------------------------------
__global__ __launch_bounds__(320) void proj_gemm_kernel(
    const float* __restrict__ x,
    const float* __restrict__ w1, const float* __restrict__ b1,
    const float* __restrict__ w2, const float* __restrict__ b2,
    const float* __restrict__ w3, const float* __restrict__ b3,
    unsigned short* __restrict__ Qm, unsigned short* __restrict__ Km,
    unsigned short* __restrict__ Vm)
{
    const int b  = blockIdx.x >> 6;
    const int n0 = (blockIdx.x & 63) * 64;
    const int wave = threadIdx.x >> 6;
    const int lane = threadIdx.x & 63;
    const int cl = lane & 15, g = lane >> 4;

    const float* arow[4];
#pragma unroll
    for (int ct = 0; ct < 4; ++ct) {
        const int row = wave * 64 + ct * 16 + cl;  // 0..319
        if (row < 32)       arow[ct] = w1 + (size_t)row * 256;
        else if (row < 64)  arow[ct] = w2 + (size_t)(row - 32) * 256;
        else                arow[ct] = w3 + (size_t)(row - 64) * 256;
    }

    const float* xb = x + (size_t)b * CC * NPIX + n0 + cl;

    f32x4 acc[4][4];
#pragma unroll
    for (int ct = 0; ct < 4; ++ct)
#pragma unroll
        for (int nt = 0; nt < 4; ++nt) acc[ct][nt] = (f32x4){0.f, 0.f, 0.f, 0.f};

    for (int ks = 0; ks < 8; ++ks) {
        const int c0 = ks * 32;
        s16x8 ah[4];
#pragma unroll
        for (int ct = 0; ct < 4; ++ct) {
            const float* ap = arow[ct] + c0 + g * 8;
            f32x4 a0 = *(const f32x4*)ap;
            f32x4 a1 = *(const f32x4*)(ap + 4);
            u32x4 u;
            u[0] = cvt_pk_bf16(a0[0], a0[1]); u[1] = cvt_pk_bf16(a0[2], a0[3]);
            u[2] = cvt_pk_bf16(a1[0], a1[1]); u[3] = cvt_pk_bf16(a1[2], a1[3]);
            ah[ct] = __builtin_bit_cast(s16x8, u);
        }
#pragma unroll
        for (int nt = 0; nt < 4; ++nt) {
            const float* xp = xb + (size_t)(c0 + g * 8) * NPIX + nt * 16;
            float xe[8];
#pragma unroll
            for (int e = 0; e < 8; ++e) xe[e] = xp[(size_t)e * NPIX];
            u32x4 uh, ul;
#pragma unroll
            for (int p = 0; p < 4; ++p) {
                const unsigned int hp = cvt_pk_bf16(xe[2 * p], xe[2 * p + 1]);
                const float h0 = u2f(hp << 16);
                const float h1 = u2f(hp & 0xffff0000u);
                uh[p] = hp;
                ul[p] = cvt_pk_bf16(xe[2 * p] - h0, xe[2 * p + 1] - h1);
            }
            const s16x8 bh = __builtin_bit_cast(s16x8, uh);
            const s16x8 bl = __builtin_bit_cast(s16x8, ul);
#pragma unroll
            for (int ct = 0; ct < 4; ++ct)
                acc[ct][nt] = __builtin_amdgcn_mfma_f32_16x16x32_bf16(ah[ct], bh, acc[ct][nt], 0, 0, 0);
#pragma unroll
            for (int ct = 0; ct < 4; ++ct)
                acc[ct][nt] = __builtin_amdgcn_mfma_f32_16x16x32_bf16(ah[ct], bl, acc[ct][nt], 0, 0, 0);
        }
    }

    if (wave == 0) {
#pragma unroll
        for (int ct = 0; ct < 4; ++ct) {
#pragma unroll
            for (int nt = 0; nt < 4; ++nt) {
                const int n = n0 + nt * 16 + cl;
                const int co = ct * 16 + g * 4;
                f32x4 v = acc[ct][nt];
                if (ct < 2) {  // Q, pre-scaled by log2e
                    const float q0 = (v[0] + b1[co + 0]) * LOG2E;
                    const float q1 = (v[1] + b1[co + 1]) * LOG2E;
                    const float q2 = (v[2] + b1[co + 2]) * LOG2E;
                    const float q3 = (v[3] + b1[co + 3]) * LOG2E;
                    u32x2 dd = {cvt_pk_bf16(q0, q1), cvt_pk_bf16(q2, q3)};
                    *(u32x2*)(Qm + ((size_t)b * NPIX + n) * 32 + co) = dd;
                } else {
                    const int ko = co - 32;
                    const float k0 = v[0] + b2[ko + 0];
                    const float k1 = v[1] + b2[ko + 1];
                    const float k2 = v[2] + b2[ko + 2];
                    const float k3 = v[3] + b2[ko + 3];
                    u32x2 dd = {cvt_pk_bf16(k0, k1), cvt_pk_bf16(k2, k3)};
                    *(u32x2*)(Km + ((size_t)b * NPIX + n) * 32 + ko) = dd;
                }
            }
        }
    } else {
        const int cvb = (wave - 1) * 64;
#pragma unroll
        for (int ct = 0; ct < 4; ++ct) {
#pragma unroll
            for (int nt = 0; nt < 4; ++nt) {
                const int n = n0 + nt * 16 + cl;
                const int cv = cvb + ct * 16 + g * 4;
#pragma unroll
                for (int r = 0; r < 4; ++r)
                    Vm[((size_t)b * CC + cv + r) * NPIX + n] = f2bf(acc[ct][nt][r] + b3[cv + r]);
            }
        }
    }
}

// ---------------------------------------------------------------------------
// attn v3: wave w owns channels [w*64, w*64+64) for ALL 64 q of the block, and
// owns softmax for the private q-slice [w*16, w*16+16). P + per-q alpha shared
// via LDS. K read direct from L2 (no staging). V reg-prefetched one tile ahead
// (T14). 2 barriers/iter. LDS 41KB -> 3 blocks/CU.
// grid: 512 blocks (8 batches x 64 q-blocks), 256 threads = 4 waves
// ---------------------------------------------------------------------------
__global__ __launch_bounds__(256, 3) void attn_kernel(
    const unsigned short* __restrict__ Qm, const unsigned short* __restrict__ Km,
    const unsigned short* __restrict__ Vm, const float* __restrict__ gamma,
    float* __restrict__ out)
{
    __shared__ unsigned short Vs[CC * KVB];   // [c][m] 32KB, 16B-slot XOR swizzle
    __shared__ unsigned short Ps[QB * KVB];   // [q][m]  8KB, swizzled, shared
    __shared__ float alpha_lds[QB];           // per-q rescale factor, this tile
    __shared__ float l_lds[QB];               // final softmax denominators

    // XCD swizzle: each XCD gets one batch's 64 q-blocks (K+V fit its 4MB L2)
    const int bid = ((blockIdx.x & 7) << 6) + (blockIdx.x >> 3);
    const int b = bid >> 6;
    const int q0 = (bid & 63) * QB;

    const int t = threadIdx.x;
    const int wave = t >> 6;
    const int lane = t & 63;
    const int cl = lane & 15;
    const int g = lane >> 4;
    const int c0w = wave * 64;       // this wave's channel slice
    const int qrow_own = wave * 16 + cl;  // this wave's softmax q-row (in-block)

    // Q B-frag for the private q-slice: B[k=d][col=q]
    const s16x8 qf = *(const s16x8*)(Qm + (((size_t)b * NPIX) + q0 + qrow_own) * 32 + g * 8);

    f32x4 acc[4][4];  // [qt][ct]: q = qt*16+cl, c = c0w + ct*16 + g*4 + r
#pragma unroll
    for (int qt = 0; qt < 4; ++qt)
#pragma unroll
        for (int ct = 0; ct < 4; ++ct)
            acc[qt][ct] = (f32x4){0.f, 0.f, 0.f, 0.f};

    float mrun = -__builtin_inff();
    float lrun = 0.f;

    const unsigned short* Kg = Km + (size_t)b * NPIX * 32;
    const unsigned short* Vg = Vm + (size_t)b * CC * NPIX;

    // V staging geometry: thread covers rows cr = (t>>3) + i*32, 16B chunk vin
    const int vin = t & 7;
    const int vr0 = t >> 3;
    const int vslot = (vin ^ (vr0 & 7)) << 3;  // (i*32 preserves cr&7)
    const unsigned short* vsrc = Vg + (size_t)vr0 * NPIX + vin * 8;
    unsigned short* vdst = &Vs[vr0 * 64 + vslot];

    // prologue: prefetch V tile 0 into registers (T14)
    s16x8 vreg[8];
#pragma unroll
    for (int i = 0; i < 8; ++i)
        vreg[i] = *(const s16x8*)(vsrc + (size_t)i * 32 * NPIX);

    for (int m0 = 0; m0 < NPIX; m0 += KVB) {
        __syncthreads();  // prev iter's Vs/Ps reads complete

        // commit prefetched V tile to LDS
#pragma unroll
        for (int i = 0; i < 8; ++i)
            *(s16x8*)(vdst + i * 32 * 64) = vreg[i];

        // issue next tile's V loads (in flight across compute below)
        if (m0 + KVB < NPIX) {
            const unsigned short* vs2 = vsrc + m0 + KVB;
#pragma unroll
            for (int i = 0; i < 8; ++i)
                vreg[i] = *(const s16x8*)(vs2 + (size_t)i * 32 * NPIX);
        }

        // K A-frags direct from global (L2-resident): A[row=m][k=d]
        s16x8 kf[4];
#pragma unroll
        for (int mt = 0; mt < 4; ++mt)
            kf[mt] = *(const s16x8*)(Kg + (size_t)(m0 + mt * 16 + cl) * 32 + g * 8);

        // QK^T for private q-slice: S^T tiles D[row=m][col=q]
        f32x4 s[4];
        __builtin_amdgcn_s_setprio(1);
#pragma unroll
        for (int mt = 0; mt < 4; ++mt) {
            f32x4 z = (f32x4){0.f, 0.f, 0.f, 0.f};
            s[mt] = __builtin_amdgcn_mfma_f32_16x16x32_bf16(kf[mt], qf, z, 0, 0, 0);
        }
        __builtin_amdgcn_s_setprio(0);

        // online softmax over m (log2 domain; Q pre-scaled by log2e)
        float ml = -__builtin_inff();
#pragma unroll
        for (int mt = 0; mt < 4; ++mt)
#pragma unroll
            for (int r = 0; r < 4; ++r) ml = fmaxf(ml, s[mt][r]);
        ml = fmaxf(ml, __shfl_xor(ml, 16, 64));
        ml = fmaxf(ml, __shfl_xor(ml, 32, 64));

        float alpha = 1.f;
        if (!__all(ml <= mrun + 8.f)) {  // defer-max (T13)
            const float mnew = fmaxf(mrun, ml);
            alpha = __builtin_amdgcn_exp2f(mrun - mnew);
            mrun = mnew;
            lrun *= alpha;
        }
        if (g == 0) alpha_lds[qrow_own] = alpha;

        float sl = 0.f;
#pragma unroll
        for (int mt = 0; mt < 4; ++mt) {
#pragma unroll
            for (int r = 0; r < 4; ++r) {
                s[mt][r] = __builtin_amdgcn_exp2f(s[mt][r] - mrun);
                sl += s[mt][r];
            }
        }
        sl += __shfl_xor(sl, 16, 64);
        sl += __shfl_xor(sl, 32, 64);
        lrun += sl;

        // pack P slice -> shared LDS [q][m], swizzled (8B writes via cvt_pk)
#pragma unroll
        for (int mt = 0; mt < 4; ++mt) {
            u32x2 dd = {cvt_pk_bf16(s[mt][0], s[mt][1]),
                        cvt_pk_bf16(s[mt][2], s[mt][3])};
            *(u32x2*)(&Ps[qrow_own * 64 + ((mt * 16 + g * 4) ^ ((qrow_own & 7) << 3))]) = dd;
        }

        __syncthreads();  // Vs + Ps + alpha ready

        // rescale acc by per-q alpha (broadcast read; rare thanks to defer-max)
        float aq[4];
#pragma unroll
        for (int qt = 0; qt < 4; ++qt) aq[qt] = alpha_lds[qt * 16 + cl];
        if (__any(aq[0] != 1.f || aq[1] != 1.f || aq[2] != 1.f || aq[3] != 1.f)) {
#pragma unroll
            for (int qt = 0; qt < 4; ++qt)
#pragma unroll
                for (int ct = 0; ct < 4; ++ct) acc[qt][ct] *= aq[qt];
        }

        // PV: acc[qt][ct] += mfma(A=V[c][m], B=P^T[m][q])
#pragma unroll
        for (int ch = 0; ch < 2; ++ch) {
            s16x8 pb[4];
#pragma unroll
            for (int qt = 0; qt < 4; ++qt) {
                const int qr = qt * 16 + cl;
                pb[qt] = *(const s16x8*)(&Ps[qr * 64 + ((ch * 32 + g * 8) ^ ((qr & 7) << 3))]);
            }
            __builtin_amdgcn_s_setprio(1);
#pragma unroll
            for (int ct = 0; ct < 4; ++ct) {
                const int cr = c0w + ct * 16 + cl;
                s16x8 av = *(const s16x8*)(&Vs[cr * 64 + ((ch * 32 + g * 8) ^ ((cr & 7) << 3))]);
#pragma unroll
                for (int qt = 0; qt < 4; ++qt)
                    acc[qt][ct] = __builtin_amdgcn_mfma_f32_16x16x32_bf16(av, pb[qt], acc[qt][ct], 0, 0, 0);
            }
            __builtin_amdgcn_s_setprio(0);
        }
    }

    // share final softmax denominators across waves
    __syncthreads();
    if (lane < 16) l_lds[wave * 16 + lane] = lrun;
    __syncthreads();

    // epilogue: coalesced [b][c][n] stores; second output = gamma*val
    const float gm = gamma[0];
    float* out2 = out + (size_t)NB * CC * NPIX;
#pragma unroll
    for (int qt = 0; qt < 4; ++qt) {
        const float inv = 1.f / l_lds[qt * 16 + cl];
        const int n = q0 + qt * 16 + cl;
#pragma unroll
        for (int ct = 0; ct < 4; ++ct) {
#pragma unroll
            for (int r = 0; r < 4; ++r) {
                const int chn = c0w + ct * 16 + g * 4 + r;
                const float val = acc[qt][ct][r] * inv;
                const size_t idx = ((size_t)b * CC + chn) * NPIX + n;
                out[idx] = val;
                out2[idx] = gm * val;
            }
        }
    }
}

// ---------------------------------------------------------------------------
extern "C" void kernel_launch(void* const* d_in, const int* in_sizes, int n_in,
                              void* d_out, int out_size, void* d_ws, size_t ws_size,
                              hipStream_t stream) {
    (void)in_sizes; (void)n_in; (void)out_size; (void)ws_size;
    const float* x     = (const float*)d_in[0];
    const float* w1    = (const float*)d_in[1];
    const float* b1    = (const float*)d_in[2];
    const float* w2    = (const float*)d_in[3];
    const float* b2    = (const float*)d_in[4];
    const float* w3    = (const float*)d_in[5];
    const float* b3    = (const float*)d_in[6];
    const float* gamma = (const float*)d_in[7];
    float* out = (float*)d_out;

    unsigned short* Qm = (unsigned short*)d_ws;                       // 2 MB
    unsigned short* Km = Qm + (size_t)NB * NPIX * 32;                 // 2 MB
    unsigned short* Vm = Km + (size_t)NB * NPIX * 32;                 // 16 MB

    proj_gemm_kernel<<<NB * 64, 320, 0, stream>>>(x, w1, b1, w2, b2, w3, b3, Qm, Km, Vm);
    attn_kernel<<<NB * 64, 256, 0, stream>>>(Qm, Km, Vm, gamma, out);
}